// Round 5
// baseline (6606.212 us; speedup 1.0000x reference)
//
#include <hip/hip_runtime.h>

// ---------------------------------------------------------------------------
// Scaled HMM forward, B=32 rows, T=10000 serial steps, N=132 states.
// ROUND-5 REDESIGN: one WAVE per batch row. 32 blocks x 64 threads.
//  - lane l owns output states 2l, 2l+1 (dot2 over 66 alpha-pairs)
//  - alpha (f16 pairs, ~sum=128) lives in LDS row sY[68]; broadcast to all
//    lanes via 17 uniform-address ds_read_b128 (same-addr = conflict-free)
//  - A columns in VGPRs as h2 (132 regs), consumed directly by v_dot2_f32_f16
//  - states 128..131: per-lane partial dot2 + packed-f16 xor-butterfly;
//    lane 0 writes pairs 64/65
//  - sum(y) for scaling: butterfly of own-pair + 2 dot2 on extra chunk;
//    1-step-lag scale g = 128*rcp(ps), exact log bookkeeping (round-4 verified)
//  - ZERO barriers, ZERO readlanes; single-wave in-order LDS
// ---------------------------------------------------------------------------

typedef _Float16 half_t;
typedef half_t h2 __attribute__((ext_vector_type(2)));

#define FDOT2(a, b, acc) __builtin_amdgcn_fdot2((a), (b), (acc), false)

#define NS 132
#define NA 126
#define NPAIR 66       // real alpha pairs
#define NP 68          // padded pairs in sY (66 real + 2 zero)
#define EMS 68         // Em row stride (uints)
#define TLEN 10000
#define NBATCH 32

// workspace layout (bytes)
#define OBS_OFF 0                        // 32*10000*2      = 640000
#define AH_OFF  640000                   // 66*64 uint2     = 33792
#define AX_OFF  (640000 + 33792)         // 64 uint4        = 1024
#define EM_OFF  (640000 + 33792 + 1024)  // 126*68 uint     = 34272

static __device__ __forceinline__ h2 bch2(unsigned int u) {
    return __builtin_bit_cast(h2, u);
}
static __device__ __forceinline__ h2 bch2f(float f) {
    return __builtin_bit_cast(h2, f);
}
static __device__ __forceinline__ unsigned int bcu(h2 v) {
    return __builtin_bit_cast(unsigned int, v);
}
static __device__ __forceinline__ h2 pkrtz(float a, float b) {
    return __builtin_bit_cast(h2, __builtin_amdgcn_cvt_pkrtz(a, b));
}
static __device__ __forceinline__ h2 shfl_xor_h2(h2 v, int off) {
    int u = __shfl_xor(__builtin_bit_cast(int, v), off, 64);
    return __builtin_bit_cast(h2, u);
}

// ---------------------------------------------------------------------------
// one-hot [B*T, 126] fp32 -> index [B*T] ushort. One wave per (b,t).
// ---------------------------------------------------------------------------
__global__ void onehot_to_idx_kernel(const float* __restrict__ x,
                                     unsigned short* __restrict__ obs, int total) {
    int wid  = (int)((blockIdx.x * blockDim.x + threadIdx.x) >> 6);
    int lane = threadIdx.x & 63;
    if (wid >= total) return;
    const float* row = x + (size_t)wid * NA;
    float v0 = row[lane];
    float v1 = (lane < NA - 64) ? row[64 + lane] : 0.0f;
    unsigned long long b0 = __ballot(v0 > 0.5f);
    unsigned long long b1 = __ballot(v1 > 0.5f);
    int idx = b0 ? (__ffsll(b0) - 1) : (64 + __ffsll(b1) - 1);
    if (lane == 0) obs[wid] = (unsigned short)idx;
}

// Ah2[p*64+l] = { h2(A[2p][2l],A[2p+1][2l]), h2(A[2p][2l+1],A[2p+1][2l+1]) }
__global__ void pack_Ah2_kernel(const float* __restrict__ A, uint2* __restrict__ Ah2) {
    int idx = blockIdx.x * 256 + threadIdx.x;
    if (idx >= NPAIR * 64) return;
    int p = idx >> 6, l = idx & 63;
    int i0 = 2 * p, i1 = 2 * p + 1, j0 = 2 * l, j1 = 2 * l + 1;
    h2 c0 = {(half_t)A[i0 * NS + j0], (half_t)A[i1 * NS + j0]};
    h2 c1 = {(half_t)A[i0 * NS + j1], (half_t)A[i1 * NS + j1]};
    Ah2[idx] = make_uint2(bcu(c0), bcu(c1));
}

// AhX[l] = { h2(A[2l][128+s], A[2l+1][128+s]) : s=0..3 }
__global__ void pack_AhX_kernel(const float* __restrict__ A, uint4* __restrict__ AhX) {
    int l = threadIdx.x;
    if (l >= 64) return;
    unsigned int r[4];
#pragma unroll
    for (int s = 0; s < 4; ++s) {
        h2 v = {(half_t)A[(2 * l) * NS + 128 + s], (half_t)A[(2 * l + 1) * NS + 128 + s]};
        r[s] = bcu(v);
    }
    AhX[l] = make_uint4(r[0], r[1], r[2], r[3]);
}

// EmG[o*EMS+p] = h2(B[2p][o], B[2p+1][o]) for p<66, else 0
__global__ void pack_Em_kernel(const float* __restrict__ B, unsigned int* __restrict__ EmG) {
    int idx = blockIdx.x * 256 + threadIdx.x;
    if (idx >= NA * EMS) return;
    int o = idx / EMS, p = idx % EMS;
    h2 v = {(half_t)0.f, (half_t)0.f};
    if (p < NPAIR) {
        v.x = (half_t)B[(2 * p) * NA + o];
        v.y = (half_t)B[(2 * p + 1) * NA + o];
    }
    EmG[idx] = bcu(v);
}

// ---------------------------------------------------------------------------
// The serial scan. 32 blocks x 64 threads (ONE wave per batch row).
// ---------------------------------------------------------------------------
__global__ __launch_bounds__(64)
__attribute__((amdgpu_waves_per_eu(1, 1)))
void hmm_forward_kernel(
    const uint2* __restrict__ Ah2,
    const uint4* __restrict__ AhX,
    const unsigned int* __restrict__ EmG,
    const float* __restrict__ I0,
    const unsigned short* __restrict__ obs,
    float* __restrict__ out)
{
    __shared__ __align__(16) unsigned int sEm[NA * EMS];  // 34272 B
    __shared__ __align__(16) h2 sY[NP];                   // 272 B

    const int l = threadIdx.x;
    const int b = blockIdx.x;

    // stage packed emission table into LDS
    {
        const uint4* src = (const uint4*)EmG;
        uint4* dst = (uint4*)sEm;
        for (int k = l; k < (NA * EMS) / 4; k += 64) dst[k] = src[k];
    }

    // A columns 2l, 2l+1 in registers: 132 h2 (+4 extra-state h2)
    h2 a0[NPAIR], a1[NPAIR];
#pragma unroll
    for (int p = 0; p < NPAIR; ++p) {
        uint2 v = Ah2[p * 64 + l];
        a0[p] = bch2(v.x);
        a1[p] = bch2(v.y);
    }
    uint4 vx = AhX[l];
    const h2 ax0 = bch2(vx.x), ax1 = bch2(vx.y), ax2 = bch2(vx.z), ax3 = bch2(vx.w);

    const unsigned short* ob = obs + b * TLEN;
    int o0 = (int)ob[0];
    int o1 = (int)ob[1];
    float2 i0p = *(const float2*)&I0[2 * l];
    __syncthreads();  // Em staged

    // ---- t = 0: y0 = 128 * I0 * B[:,o0] ----
    h2 em0 = bch2(sEm[o0 * EMS + l]);
    h2 y_own = pkrtz(i0p.x * (float)em0.x * 128.f, i0p.y * (float)em0.y * 128.f);
    sY[l] = y_own;
    if (l < 2) {  // pairs 64,65 = states 128..131
        float2 ix = *(const float2*)&I0[128 + 2 * l];
        h2 ex = bch2(sEm[o0 * EMS + 64 + l]);
        sY[64 + l] = pkrtz(ix.x * (float)ex.x * 128.f, ix.y * (float)ex.y * 128.f);
    }
    if (l >= 2 && l < 4) {  // pairs 66,67 stay zero forever
        h2 z = {(half_t)0.f, (half_t)0.f};
        sY[64 + l] = z;
    }

    // broadcast y0 + prefetch operands for t = 1
    float4 bq[17];
    const float4* yb = (const float4*)sY;
#pragma unroll
    for (int q = 0; q < 17; ++q) bq[q] = yb[q];
    h2 em = bch2(sEm[o1 * EMS + l]);
    uint2 emXu = *(const uint2*)&sEm[o1 * EMS + 64];
    int o_nx = (int)ob[2];

    const h2 ones = {(half_t)1.f, (half_t)1.f};
    float ll = 0.f, lp = 1.f;

    for (int t = 1; t < TLEN; ++t) {
        // ps = sum(y_{t-1}): butterfly of own pairs + extra chunk (off crit path)
        float ps = FDOT2(y_own, ones, 0.f);
#pragma unroll
        for (int off = 32; off; off >>= 1) ps += __shfl_xor(ps, off, 64);
        ps += FDOT2(bch2f(bq[16].x), ones, FDOT2(bch2f(bq[16].y), ones, 0.f));

        // states 128..131: per-lane partials + packed-f16 butterfly
        float p0 = FDOT2(y_own, ax0, 0.f);
        float p1 = FDOT2(y_own, ax1, 0.f);
        float p2 = FDOT2(y_own, ax2, 0.f);
        float p3 = FDOT2(y_own, ax3, 0.f);
        h2 e01 = pkrtz(p0, p1), e23 = pkrtz(p2, p3);
#pragma unroll
        for (int off = 32; off; off >>= 1) {
            e01 = e01 + shfl_xor_h2(e01, off);
            e23 = e23 + shfl_xor_h2(e23, off);
        }

        // main dots: s_j = sum_i y_i * A[i][j], j = 2l (even), 2l+1 (odd)
        float se0 = 0.f, se1 = 0.f, so0 = 0.f, so1 = 0.f;
#pragma unroll
        for (int q = 0; q < 16; ++q) {
            h2 y0 = bch2f(bq[q].x), y1 = bch2f(bq[q].y);
            h2 y2 = bch2f(bq[q].z), y3 = bch2f(bq[q].w);
            se0 = FDOT2(y0, a0[4 * q + 0], se0);
            se1 = FDOT2(y1, a0[4 * q + 1], se1);
            se0 = FDOT2(y2, a0[4 * q + 2], se0);
            se1 = FDOT2(y3, a0[4 * q + 3], se1);
            so0 = FDOT2(y0, a1[4 * q + 0], so0);
            so1 = FDOT2(y1, a1[4 * q + 1], so1);
            so0 = FDOT2(y2, a1[4 * q + 2], so0);
            so1 = FDOT2(y3, a1[4 * q + 3], so1);
        }
        {   // chunk 16: pairs 64,65 real; 66,67 are zero -> skipped
            h2 y0 = bch2f(bq[16].x), y1 = bch2f(bq[16].y);
            se0 = FDOT2(y0, a0[64], se0);
            se1 = FDOT2(y1, a0[65], se1);
            so0 = FDOT2(y0, a1[64], so0);
            so1 = FDOT2(y1, a1[65], so1);
        }
        float s_e = se0 + se1, s_o = so0 + so1;

        float g = 128.f * __builtin_amdgcn_rcpf(ps);
        lp *= ps;
        if ((t & 3) == 0) { ll += __logf(lp); lp = 1.f; }

        // y_t = s * em * g ; write own pair, lane 0 writes extra pairs
        y_own = pkrtz(s_e * (float)em.x * g, s_o * (float)em.y * g);
        sY[l] = y_own;

        h2 emX0 = bch2(emXu.x), emX1 = bch2(emXu.y);
        half_t gh = (half_t)g;
        h2 gg = {gh, gh};
        h2 pair64 = e01 * emX0 * gg;
        h2 pair65 = e23 * emX1 * gg;
        if (l == 0) {
            *(uint2*)&sY[64] = make_uint2(bcu(pair64), bcu(pair65));
        }

        // re-broadcast y_t + prefetch em for t+1 (latency hides in loop tail;
        // single-wave in-order LDS: reads after writes see the new values)
        int o_use = o_nx;
        o_nx = (t + 2 < TLEN) ? (int)ob[t + 2] : 0;
#pragma unroll
        for (int q = 0; q < 17; ++q) bq[q] = yb[q];
        em = bch2(sEm[o_use * EMS + l]);
        emXu = *(const uint2*)&sEm[o_use * EMS + 64];
    }

    // epilogue: leftover lp + log(sum y_T) - 10000*log(128)
    ll += __logf(lp);
    {
        float ps = FDOT2(y_own, ones, 0.f);
#pragma unroll
        for (int off = 32; off; off >>= 1) ps += __shfl_xor(ps, off, 64);
        ps += FDOT2(bch2f(bq[16].x), ones, FDOT2(bch2f(bq[16].y), ones, 0.f));
        ll += __logf(ps);
    }
    ll -= 48520.30263919617f;  // 10000 * ln(128)

    if (l == 0) out[b] = ll;
}

// ---------------------------------------------------------------------------
extern "C" void kernel_launch(void* const* d_in, const int* in_sizes, int n_in,
                              void* d_out, int out_size, void* d_ws, size_t ws_size,
                              hipStream_t stream) {
    const float* x  = (const float*)d_in[0];  // [32,10000,126] one-hot fp32
    const float* A  = (const float*)d_in[1];  // [132,132]
    const float* Bm = (const float*)d_in[2];  // [132,126]
    const float* I0 = (const float*)d_in[3];  // [132]
    float* out = (float*)d_out;               // [32] fp32

    char* ws = (char*)d_ws;
    unsigned short* obs = (unsigned short*)(ws + OBS_OFF);
    uint2* Ah2 = (uint2*)(ws + AH_OFF);
    uint4* AhX = (uint4*)(ws + AX_OFF);
    unsigned int* EmG = (unsigned int*)(ws + EM_OFF);

    const int total = NBATCH * TLEN;
    onehot_to_idx_kernel<<<(total + 3) / 4, 256, 0, stream>>>(x, obs, total);
    pack_Ah2_kernel<<<(NPAIR * 64 + 255) / 256, 256, 0, stream>>>(A, Ah2);
    pack_AhX_kernel<<<1, 64, 0, stream>>>(A, AhX);
    pack_Em_kernel<<<(NA * EMS + 255) / 256, 256, 0, stream>>>(Bm, EmG);
    hmm_forward_kernel<<<NBATCH, 64, 0, stream>>>(Ah2, AhX, EmG, I0, obs, out);
}